// Round 7
// baseline (180.027 us; speedup 1.0000x reference)
//
#include <hip/hip_runtime.h>
#include <cfloat>
#include <cmath>
#include <stdint.h>

#define NROWS 32768
#define DIM   256
#define KC    1024

typedef short bf16x8 __attribute__((ext_vector_type(8)));
typedef float f32x4  __attribute__((ext_vector_type(4)));
typedef float f32x2  __attribute__((ext_vector_type(2)));

__device__ inline unsigned short f2bf(float f) {
    unsigned u = __float_as_uint(f);
    u = (u + 0x7fffu + ((u >> 16) & 1u)) >> 16;   // RNE
    return (unsigned short)u;
}

// ---------- prep_w: pack w (hi bf16) into MFMA B-frag order + transpose ----------
__global__ __launch_bounds__(256) void prep_w(const float* __restrict__ w,
                                              uint4* __restrict__ wph,
                                              float* __restrict__ wT) {
    const int t = blockIdx.x * 256 + threadIdx.x;   // 0..32767
    const int l = t & 63;
    const int ks = (t >> 6) & 7;
    const int ctg = t >> 9;
    const int c = ctg * 16 + (l & 15);
    const int kbase = ks * 32 + ((l >> 4) << 3);
    union { unsigned short u[8]; uint4 v; } H;
#pragma unroll
    for (int j = 0; j < 8; ++j) {
        float v = w[(size_t)(kbase + j) * KC + c];
        H.u[j] = f2bf(v);
        wT[(size_t)c * DIM + kbase + j] = v;
    }
    wph[t] = H.v;
}

// ---------- wnorm from wT (fp64 + fp32 copy) ----------
__global__ __launch_bounds__(256) void wnorm_kernel(const float* __restrict__ wT,
                                                    double* __restrict__ wnorm64,
                                                    float* __restrict__ wnormf) {
    const int k = blockIdx.x * 256 + threadIdx.x;
    const float* p = wT + (size_t)k * DIM;
    double acc = 0.0;
#pragma unroll 8
    for (int d = 0; d < DIM; ++d) acc += (double)p[d] * (double)p[d];
    wnorm64[k] = acc;
    wnormf[k] = (float)acc;
}

// ---------- kernel A: argmin only (R5 structure, no epilogue) ----------
__global__ __launch_bounds__(256, 2) void vq_argmin(
    const float* __restrict__ x,
    const char* __restrict__ wph,
    const float* __restrict__ wT,
    const double* __restrict__ wnorm64, const float* __restrict__ wnormf,
    int* __restrict__ ws_idx)
{
    __shared__ char ldsbuf[65536];    // double buffer: [0,32K) and [32K,64K)

    const int t = threadIdx.x;
    const int l = t & 63;
    const int wv = t >> 6;
    const int blockRow0 = blockIdx.x * 64;
    const int r0 = blockRow0 + wv * 16;

    // ---- A fragments: 16 rows x 256 k, hi bf16, converted in-register ----
    bf16x8 ah[8];
    {
        const float* xb = x + (size_t)(r0 + (l & 15)) * DIM + ((l >> 4) << 3);
#pragma unroll
        for (int ks = 0; ks < 8; ++ks) {
            float4 p0 = *(const float4*)(xb + ks * 32);
            float4 p1 = *(const float4*)(xb + ks * 32 + 4);
            float f[8] = {p0.x, p0.y, p0.z, p0.w, p1.x, p1.y, p1.z, p1.w};
            union { unsigned short u[8]; bf16x8 v; } H;
#pragma unroll
            for (int j = 0; j < 8; ++j) H.u[j] = f2bf(f[j]);
            ah[ks] = H.v;
        }
    }

    // top-3 per row (4 rows per lane)
    float tv0[4], tv1[4], tv2[4];
    int   tk0[4], tk1[4], tk2[4];
#pragma unroll
    for (int r = 0; r < 4; ++r) { tv0[r] = tv1[r] = tv2[r] = FLT_MAX; tk0[r] = tk1[r] = tk2[r] = 0; }

    // ---- K-loop over 16 col-groups of 64 cols, double-buffered staging ----
    {
        const char* g0 = wph + wv * 1024 + l * 16;
        char* lp0 = ldsbuf + wv * 1024 + l * 16;
#pragma unroll
        for (int i = 0; i < 8; ++i)
            __builtin_amdgcn_global_load_lds(
                (const __attribute__((address_space(1))) void*)(g0 + i * 4096),
                (__attribute__((address_space(3))) void*)(lp0 + i * 4096), 16, 0, 0);
    }
    __syncthreads();

    int cur = 0;
    for (int cg = 0; cg < 16; ++cg) {
        if (cg + 1 < 16) {
            const char* g = wph + (size_t)(cg + 1) * 32768 + wv * 1024 + l * 16;
            char* lp = ldsbuf + (cur ^ 1) * 32768 + wv * 1024 + l * 16;
#pragma unroll
            for (int i = 0; i < 8; ++i)
                __builtin_amdgcn_global_load_lds(
                    (const __attribute__((address_space(1))) void*)(g + i * 4096),
                    (__attribute__((address_space(3))) void*)(lp + i * 4096), 16, 0, 0);
        }

        f32x4 acc[4];
#pragma unroll
        for (int ct = 0; ct < 4; ++ct) acc[ct] = (f32x4){0.f, 0.f, 0.f, 0.f};

#pragma unroll
        for (int ks = 0; ks < 8; ++ks) {
#pragma unroll
            for (int ct = 0; ct < 4; ++ct) {
                bf16x8 bh = *(const bf16x8*)(ldsbuf + cur * 32768 + ((ct * 8 + ks) * 64 + l) * 16);
                acc[ct] = __builtin_amdgcn_mfma_f32_16x16x32_bf16(ah[ks], bh, acc[ct], 0, 0, 0);
            }
        }

#pragma unroll
        for (int ct = 0; ct < 4; ++ct) {
            const int k = (cg * 4 + ct) * 16 + (l & 15);
            const float wn = wnormf[k];
#pragma unroll
            for (int r = 0; r < 4; ++r) {
                float s = wn - 2.0f * acc[ct][r];
                if (s < tv2[r]) {
                    if (s < tv1[r]) {
                        tv2[r] = tv1[r]; tk2[r] = tk1[r];
                        if (s < tv0[r]) { tv1[r] = tv0[r]; tk1[r] = tk0[r]; tv0[r] = s; tk0[r] = k; }
                        else            { tv1[r] = s;      tk1[r] = k; }
                    } else { tv2[r] = s; tk2[r] = k; }
                }
            }
        }

        if (cg + 1 < 16) __syncthreads();
        cur ^= 1;
    }

    // ---- cross-lane fp32 rowmin ----
    float rowmin[4];
#pragma unroll
    for (int r = 0; r < 4; ++r) {
        float v = tv0[r];
#pragma unroll
        for (int m = 1; m <= 8; m <<= 1) v = fminf(v, __shfl_xor(v, m));
        rowmin[r] = v;
    }

    // ---- fp64 refine of candidates within margin ----
    const float margin = 0.125f;
    double bestv[4]; int bestk[4];
#pragma unroll
    for (int r = 0; r < 4; ++r) { bestv[r] = 1e300; bestk[r] = 0x7FFFFFFF; }
    for (int r = 0; r < 4; ++r) {
        const int row = r0 + ((l >> 4) << 2) + r;
        const float4* x4 = (const float4*)(x + (size_t)row * DIM);
        float cv[3] = {tv0[r], tv1[r], tv2[r]};
        int   ck[3] = {tk0[r], tk1[r], tk2[r]};
        for (int j = 0; j < 3; ++j) {
            if (cv[j] <= rowmin[r] + margin) {
                const int k = ck[j];
                const float4* w4 = (const float4*)(wT + (size_t)k * DIM);
                double d0 = 0, d1 = 0, d2 = 0, d3 = 0;
#pragma unroll 4
                for (int i = 0; i < 64; ++i) {
                    float4 a = x4[i], b = w4[i];
                    d0 = fma((double)a.x, (double)b.x, d0);
                    d1 = fma((double)a.y, (double)b.y, d1);
                    d2 = fma((double)a.z, (double)b.z, d2);
                    d3 = fma((double)a.w, (double)b.w, d3);
                }
                double s64 = wnorm64[k] - 2.0 * ((d0 + d1) + (d2 + d3));
                if (s64 < bestv[r] || (s64 == bestv[r] && k < bestk[r])) { bestv[r] = s64; bestk[r] = k; }
            }
        }
    }

    // ---- cross-lane fp64 argmin; write per-row index ----
#pragma unroll
    for (int r = 0; r < 4; ++r) {
        double v = bestv[r]; int k = bestk[r];
#pragma unroll
        for (int m = 1; m <= 8; m <<= 1) {
            double ov = __shfl_xor(v, m); int ok = __shfl_xor(k, m);
            if (ov < v || (ov == v && ok < k)) { v = ov; k = ok; }
        }
        if ((l & 15) == 0) {
            const int row = r0 + ((l >> 4) << 2) + r;
            ws_idx[row] = k;
        }
    }
}

// ---------- kernel B: streaming epilogue, full occupancy ----------
__global__ __launch_bounds__(256) void vq_epilogue(
    const float* __restrict__ x, const float* __restrict__ wT,
    const int* __restrict__ ws_idx,
    float* __restrict__ out_q, float* __restrict__ out_idx, float* __restrict__ out_enc,
    int* __restrict__ counts, double* __restrict__ loss_sum)
{
    const int t = threadIdx.x;
    const int l = t & 63;
    const int wv = t >> 6;
    __shared__ double wsum[4];

    double ls0 = 0.0, ls1 = 0.0, ls2 = 0.0, ls3 = 0.0;
    const int stride = gridDim.x * 4;
    for (int row = blockIdx.x * 4 + wv; row < NROWS; row += stride) {
        int k = ws_idx[row];                          // uniform per wave
        k = __builtin_amdgcn_readfirstlane(k);        // scalar base for wT row
        float4 xv = ((const float4*)(x  + (size_t)row * DIM))[l];
        float4 qv = ((const float4*)(wT + (size_t)k  * DIM))[l];
        f32x4 o = {xv.x + (qv.x - xv.x), xv.y + (qv.y - xv.y),
                   xv.z + (qv.z - xv.z), xv.w + (qv.w - xv.w)};
        __builtin_nontemporal_store(o, (f32x4*)(out_q + (size_t)row * DIM) + l);
        double dx = (double)qv.x - (double)xv.x; ls0 = fma(dx, dx, ls0);
        dx = (double)qv.y - (double)xv.y; ls1 = fma(dx, dx, ls1);
        dx = (double)qv.z - (double)xv.z; ls2 = fma(dx, dx, ls2);
        dx = (double)qv.w - (double)xv.w; ls3 = fma(dx, dx, ls3);
        // one-hot zeros: coalesced f32x2 stores (512 contiguous B / instr)
        f32x2* er2 = (f32x2*)(out_enc + (size_t)row * KC);
        f32x2 z = {0.f, 0.f};
#pragma unroll
        for (int i = 0; i < 8; ++i)
            __builtin_nontemporal_store(z, er2 + i * 64 + l);
        // the 1.0: same lane that wrote the covering f32x2 (program order)
        if (l == ((k >> 1) & 63)) out_enc[(size_t)row * KC + k] = 1.0f;
        if (l == 0) {
            out_idx[row] = (float)k;
            atomicAdd(&counts[k], 1);
        }
    }
    double lsum = (ls0 + ls1) + (ls2 + ls3);
#pragma unroll
    for (int off = 32; off > 0; off >>= 1) lsum += __shfl_down(lsum, off);
    if (l == 0) wsum[wv] = lsum;
    __syncthreads();
    if (t == 0) atomicAdd(loss_sum, wsum[0] + wsum[1] + wsum[2] + wsum[3]);
}

// ---------- finalize ----------
__global__ __launch_bounds__(1024) void final_kernel(const int* __restrict__ counts,
                                                     const double* __restrict__ loss_sum,
                                                     float* __restrict__ out_loss,
                                                     float* __restrict__ out_ppl) {
    const int t = threadIdx.x;
    double p = (double)counts[t] * (1.0 / 32768.0);
    double term = -p * log(p + 1e-10);
#pragma unroll
    for (int off = 32; off > 0; off >>= 1) term += __shfl_down(term, off);
    __shared__ double ws[16];
    if ((t & 63) == 0) ws[t >> 6] = term;
    __syncthreads();
    if (t == 0) {
        double s = 0.0;
        for (int i = 0; i < 16; ++i) s += ws[i];
        *out_ppl = (float)exp(s);
        *out_loss = (float)(1.25 * loss_sum[0] * (1.0 / 8388608.0));
    }
}

extern "C" void kernel_launch(void* const* d_in, const int* in_sizes, int n_in,
                              void* d_out, int out_size, void* d_ws, size_t ws_size,
                              hipStream_t stream) {
    const float* x = (const float*)d_in[0];   // [32,32,32,256] fp32
    const float* w = (const float*)d_in[1];   // [256,1024] fp32

    float* out = (float*)d_out;
    float* out_q    = out;                        // 8388608
    float* out_loss = out + 8388608;              // 1
    float* out_ppl  = out + 8388609;              // 1
    float* out_enc  = out + 8388610;              // 33554432
    float* out_idx  = out + 8388610 + 33554432;   // 32768

    char* wsb = (char*)d_ws;
    double* loss_sum = (double*)(wsb + 0);
    int*    counts   = (int*)(wsb + 64);          // 4096 B
    double* wnorm64  = (double*)(wsb + 4160);     // 8192 B
    float*  wnormf   = (float*)(wsb + 12352);     // 4096 B
    float*  wT       = (float*)(wsb + 16448);     // 1 MB
    uint4*  wph      = (uint4*)(wsb + 1065024);   // 512 KB
    int*    ws_idx   = (int*)(wsb + 1589312);     // 128 KB

    (void)hipMemsetAsync(d_ws, 0, 4160, stream);  // loss_sum + counts

    prep_w<<<128, 256, 0, stream>>>(w, wph, wT);
    wnorm_kernel<<<4, 256, 0, stream>>>(wT, wnorm64, wnormf);
    vq_argmin<<<512, 256, 0, stream>>>(x, (const char*)wph, wT, wnorm64, wnormf, ws_idx);
    vq_epilogue<<<2048, 256, 0, stream>>>(x, wT, ws_idx, out_q, out_idx, out_enc,
                                          counts, loss_sum);
    final_kernel<<<1, 1024, 0, stream>>>(counts, loss_sum, out_loss, out_ppl);
}

// Round 8
// 138.437 us; speedup vs baseline: 1.3004x; 1.3004x over previous
//
#include <hip/hip_runtime.h>
#include <cfloat>
#include <cmath>
#include <stdint.h>

#define NROWS 32768
#define DIM   256
#define KC    1024

typedef short bf16x8 __attribute__((ext_vector_type(8)));
typedef float f32x4  __attribute__((ext_vector_type(4)));
typedef float f32x2  __attribute__((ext_vector_type(2)));

__device__ inline unsigned short f2bf(float f) {
    unsigned u = __float_as_uint(f);
    u = (u + 0x7fffu + ((u >> 16) & 1u)) >> 16;   // RNE
    return (unsigned short)u;
}

// ---------- prep_w: pack w (hi bf16) into MFMA B-frag order + transpose ----------
__global__ __launch_bounds__(256) void prep_w(const float* __restrict__ w,
                                              uint4* __restrict__ wph,
                                              float* __restrict__ wT) {
    const int t = blockIdx.x * 256 + threadIdx.x;   // 0..32767
    const int l = t & 63;
    const int ks = (t >> 6) & 7;
    const int ctg = t >> 9;
    const int c = ctg * 16 + (l & 15);
    const int kbase = ks * 32 + ((l >> 4) << 3);
    union { unsigned short u[8]; uint4 v; } H;
#pragma unroll
    for (int j = 0; j < 8; ++j) {
        float v = w[(size_t)(kbase + j) * KC + c];
        H.u[j] = f2bf(v);
        wT[(size_t)c * DIM + kbase + j] = v;
    }
    wph[t] = H.v;
}

// ---------- wnorm from wT (fp64 + fp32 copy) ----------
__global__ __launch_bounds__(256) void wnorm_kernel(const float* __restrict__ wT,
                                                    double* __restrict__ wnorm64,
                                                    float* __restrict__ wnormf) {
    const int k = blockIdx.x * 256 + threadIdx.x;
    const float* p = wT + (size_t)k * DIM;
    double acc = 0.0;
#pragma unroll 8
    for (int d = 0; d < DIM; ++d) acc += (double)p[d] * (double)p[d];
    wnorm64[k] = acc;
    wnormf[k] = (float)acc;
}

// ---------- kernel A: MFMA screen, split-K x2, candidate lists out ----------
// block = (rowtile = bid>>1, part p = bid&1). Part p covers cols [p*512, p*512+512).
// 16 staging groups of 32 cols (16KB), 2x16KB LDS double buffer -> 4 blocks/CU.
__global__ __launch_bounds__(256, 4) void vq_screen(
    const float* __restrict__ x,
    const char* __restrict__ wph,
    const float* __restrict__ wnormf,
    int* __restrict__ cand)
{
    __shared__ char ldsbuf[32768];

    const int t = threadIdx.x;
    const int l = t & 63;
    const int wv = t >> 6;
    const int rowtile = blockIdx.x >> 1;
    const int p = blockIdx.x & 1;
    const int r0 = rowtile * 64 + wv * 16;
    const size_t pbase = (size_t)p * 262144;   // part offset into wph (bytes)

    // ---- A fragments: 16 rows x 256 k, hi bf16, converted in-register ----
    bf16x8 ah[8];
    {
        const float* xb = x + (size_t)(r0 + (l & 15)) * DIM + ((l >> 4) << 3);
#pragma unroll
        for (int ks = 0; ks < 8; ++ks) {
            float4 p0 = *(const float4*)(xb + ks * 32);
            float4 p1 = *(const float4*)(xb + ks * 32 + 4);
            float f[8] = {p0.x, p0.y, p0.z, p0.w, p1.x, p1.y, p1.z, p1.w};
            union { unsigned short u[8]; bf16x8 v; } H;
#pragma unroll
            for (int j = 0; j < 8; ++j) H.u[j] = f2bf(f[j]);
            ah[ks] = H.v;
        }
    }

    float tv0[4], tv1[4], tv2[4];
    int   tk0[4], tk1[4], tk2[4];
#pragma unroll
    for (int r = 0; r < 4; ++r) { tv0[r] = tv1[r] = tv2[r] = FLT_MAX; tk0[r] = tk1[r] = tk2[r] = 0; }

    // ---- K-loop: 16 groups of 32 cols, double-buffered ----
    {
        const char* g0 = wph + pbase + wv * 4096 + l * 16;
        char* lp0 = ldsbuf + wv * 4096 + l * 16;
#pragma unroll
        for (int i = 0; i < 4; ++i)
            __builtin_amdgcn_global_load_lds(
                (const __attribute__((address_space(1))) void*)(g0 + i * 1024),
                (__attribute__((address_space(3))) void*)(lp0 + i * 1024), 16, 0, 0);
    }
    __syncthreads();

    int cur = 0;
    for (int g = 0; g < 16; ++g) {
        if (g + 1 < 16) {
            const char* gp = wph + pbase + (size_t)(g + 1) * 16384 + wv * 4096 + l * 16;
            char* lp = ldsbuf + (cur ^ 1) * 16384 + wv * 4096 + l * 16;
#pragma unroll
            for (int i = 0; i < 4; ++i)
                __builtin_amdgcn_global_load_lds(
                    (const __attribute__((address_space(1))) void*)(gp + i * 1024),
                    (__attribute__((address_space(3))) void*)(lp + i * 1024), 16, 0, 0);
        }

        f32x4 acc[2];
#pragma unroll
        for (int ct = 0; ct < 2; ++ct) acc[ct] = (f32x4){0.f, 0.f, 0.f, 0.f};

#pragma unroll
        for (int ks = 0; ks < 8; ++ks) {
#pragma unroll
            for (int ct = 0; ct < 2; ++ct) {
                bf16x8 bh = *(const bf16x8*)(ldsbuf + cur * 16384 + ((ct * 8 + ks) * 64 + l) * 16);
                acc[ct] = __builtin_amdgcn_mfma_f32_16x16x32_bf16(ah[ks], bh, acc[ct], 0, 0, 0);
            }
        }

#pragma unroll
        for (int ct = 0; ct < 2; ++ct) {
            const int k = (p * 32 + g * 2 + ct) * 16 + (l & 15);
            const float wn = wnormf[k];
#pragma unroll
            for (int r = 0; r < 4; ++r) {
                float s = wn - 2.0f * acc[ct][r];
                if (s < tv2[r]) {
                    if (s < tv1[r]) {
                        tv2[r] = tv1[r]; tk2[r] = tk1[r];
                        if (s < tv0[r]) { tv1[r] = tv0[r]; tk1[r] = tk0[r]; tv0[r] = s; tk0[r] = k; }
                        else            { tv1[r] = s;      tk1[r] = k; }
                    } else { tv2[r] = s; tk2[r] = k; }
                }
            }
        }

        if (g + 1 < 16) __syncthreads();
        cur ^= 1;
    }

    // ---- part-local rowmin ----
    float rowmin[4];
#pragma unroll
    for (int r = 0; r < 4; ++r) {
        float v = tv0[r];
#pragma unroll
        for (int m = 1; m <= 8; m <<= 1) v = fminf(v, __shfl_xor(v, m));
        rowmin[r] = v;
    }

    // ---- ballot-compacted candidate write (within margin of part min) ----
    const float margin = 0.125f;
    const int grpShift = (l >> 4) * 16;
    const unsigned laneMask = (1u << (l & 15)) - 1u;
#pragma unroll
    for (int r = 0; r < 4; ++r) {
        const int row = r0 + ((l >> 4) << 2) + r;
        int* creg = cand + ((size_t)row * 2 + p) * 8;
        const float thr = rowmin[r] + margin;
        int base = 0;
        {
            bool c = tv0[r] <= thr;
            unsigned long long bal = __ballot(c);
            unsigned grp = (unsigned)(bal >> grpShift) & 0xFFFFu;
            int pos = base + __popc(grp & laneMask);
            if (c && pos < 7) creg[1 + pos] = tk0[r];
            base += __popc(grp);
        }
        {
            bool c = tv1[r] <= thr;
            unsigned long long bal = __ballot(c);
            unsigned grp = (unsigned)(bal >> grpShift) & 0xFFFFu;
            int pos = base + __popc(grp & laneMask);
            if (c && pos < 7) creg[1 + pos] = tk1[r];
            base += __popc(grp);
        }
        {
            bool c = tv2[r] <= thr;
            unsigned long long bal = __ballot(c);
            unsigned grp = (unsigned)(bal >> grpShift) & 0xFFFFu;
            int pos = base + __popc(grp & laneMask);
            if (c && pos < 7) creg[1 + pos] = tk2[r];
            base += __popc(grp);
        }
        if ((l & 15) == 0) creg[0] = base < 7 ? base : 7;
    }
}

// ---------- kernel B: fp64 refine + streaming epilogue, full occupancy ----------
__global__ __launch_bounds__(256) void vq_final(
    const float* __restrict__ x, const float* __restrict__ wT,
    const double* __restrict__ wnorm64,
    const int* __restrict__ cand,
    float* __restrict__ out_q, float* __restrict__ out_idx, float* __restrict__ out_enc,
    int* __restrict__ counts, double* __restrict__ loss_sum)
{
    const int t = threadIdx.x;
    const int l = t & 63;
    const int wv = t >> 6;
    __shared__ double wsum[4];

    double ls0 = 0.0, ls1 = 0.0, ls2 = 0.0, ls3 = 0.0;
    const int stride = gridDim.x * 4;
    for (int row = blockIdx.x * 4 + wv; row < NROWS; row += stride) {
        const float4 xv = ((const float4*)(x + (size_t)row * DIM))[l];

        // fp64 refine over both parts' candidates (64-lane parallel dot)
        const int* c0 = cand + (size_t)row * 16;
        double best = 1e300; int bk = 0x7FFFFFFF;
#pragma unroll
        for (int part = 0; part < 2; ++part) {
            const int* cp = c0 + part * 8;
            const int n = cp[0];
            for (int c = 0; c < n; ++c) {
                const int k = cp[1 + c];
                const float4 w4 = ((const float4*)(wT + (size_t)k * DIM))[l];
                double d = (double)xv.x * (double)w4.x;
                d = fma((double)xv.y, (double)w4.y, d);
                d = fma((double)xv.z, (double)w4.z, d);
                d = fma((double)xv.w, (double)w4.w, d);
#pragma unroll
                for (int m = 32; m > 0; m >>= 1) d += __shfl_xor(d, m);
                const double s = wnorm64[k] - 2.0 * d;
                if (s < best || (s == best && k < bk)) { best = s; bk = k; }
            }
        }
        const int k = __builtin_amdgcn_readfirstlane(bk);

        const float4 qv = ((const float4*)(wT + (size_t)k * DIM))[l];
        f32x4 o = {xv.x + (qv.x - xv.x), xv.y + (qv.y - xv.y),
                   xv.z + (qv.z - xv.z), xv.w + (qv.w - xv.w)};
        __builtin_nontemporal_store(o, (f32x4*)(out_q + (size_t)row * DIM) + l);
        double dx = (double)qv.x - (double)xv.x; ls0 = fma(dx, dx, ls0);
        dx = (double)qv.y - (double)xv.y; ls1 = fma(dx, dx, ls1);
        dx = (double)qv.z - (double)xv.z; ls2 = fma(dx, dx, ls2);
        dx = (double)qv.w - (double)xv.w; ls3 = fma(dx, dx, ls3);
        // one-hot zeros: coalesced f32x2 stores (512 contiguous B / instr)
        f32x2* er2 = (f32x2*)(out_enc + (size_t)row * KC);
        f32x2 z = {0.f, 0.f};
#pragma unroll
        for (int i = 0; i < 8; ++i)
            __builtin_nontemporal_store(z, er2 + i * 64 + l);
        // the 1.0: same lane that wrote the covering f32x2 (program order)
        if (l == ((k >> 1) & 63)) out_enc[(size_t)row * KC + k] = 1.0f;
        if (l == 0) {
            out_idx[row] = (float)k;
            atomicAdd(&counts[k], 1);
        }
    }
    double lsum = (ls0 + ls1) + (ls2 + ls3);
#pragma unroll
    for (int off = 32; off > 0; off >>= 1) lsum += __shfl_down(lsum, off);
    if (l == 0) wsum[wv] = lsum;
    __syncthreads();
    if (t == 0) atomicAdd(loss_sum, wsum[0] + wsum[1] + wsum[2] + wsum[3]);
}

// ---------- finalize ----------
__global__ __launch_bounds__(1024) void final_kernel(const int* __restrict__ counts,
                                                     const double* __restrict__ loss_sum,
                                                     float* __restrict__ out_loss,
                                                     float* __restrict__ out_ppl) {
    const int t = threadIdx.x;
    double p = (double)counts[t] * (1.0 / 32768.0);
    double term = -p * log(p + 1e-10);
#pragma unroll
    for (int off = 32; off > 0; off >>= 1) term += __shfl_down(term, off);
    __shared__ double ws[16];
    if ((t & 63) == 0) ws[t >> 6] = term;
    __syncthreads();
    if (t == 0) {
        double s = 0.0;
        for (int i = 0; i < 16; ++i) s += ws[i];
        *out_ppl = (float)exp(s);
        *out_loss = (float)(1.25 * loss_sum[0] * (1.0 / 8388608.0));
    }
}

extern "C" void kernel_launch(void* const* d_in, const int* in_sizes, int n_in,
                              void* d_out, int out_size, void* d_ws, size_t ws_size,
                              hipStream_t stream) {
    const float* x = (const float*)d_in[0];   // [32,32,32,256] fp32
    const float* w = (const float*)d_in[1];   // [256,1024] fp32

    float* out = (float*)d_out;
    float* out_q    = out;                        // 8388608
    float* out_loss = out + 8388608;              // 1
    float* out_ppl  = out + 8388609;              // 1
    float* out_enc  = out + 8388610;              // 33554432
    float* out_idx  = out + 8388610 + 33554432;   // 32768

    char* wsb = (char*)d_ws;
    double* loss_sum = (double*)(wsb + 0);
    int*    counts   = (int*)(wsb + 64);          // 4096 B
    double* wnorm64  = (double*)(wsb + 4160);     // 8192 B
    float*  wnormf   = (float*)(wsb + 12352);     // 4096 B
    float*  wT       = (float*)(wsb + 16448);     // 1 MB
    uint4*  wph      = (uint4*)(wsb + 1065024);   // 512 KB
    int*    cand     = (int*)(wsb + 1589312);     // 2 MB candidate lists

    (void)hipMemsetAsync(d_ws, 0, 4160, stream);  // loss_sum + counts

    prep_w<<<128, 256, 0, stream>>>(w, wph, wT);
    wnorm_kernel<<<4, 256, 0, stream>>>(wT, wnorm64, wnormf);
    vq_screen<<<1024, 256, 0, stream>>>(x, (const char*)wph, wnormf, cand);
    vq_final<<<2048, 256, 0, stream>>>(x, wT, wnorm64, cand,
                                       out_q, out_idx, out_enc, counts, loss_sum);
    final_kernel<<<1, 1024, 0, stream>>>(counts, loss_sum, out_loss, out_ppl);
}